// Round 8
// baseline (731.799 us; speedup 1.0000x reference)
//
#include <hip/hip_runtime.h>
#include <hip/hip_bf16.h>

// 9x9 VALID conv, 4096x4096 f32 -> 4088x4088 f32, + scalar bias.
// LDS-staged: block = 256 threads = 4 waves covers a 16-row x 256-col output
// tile; input footprint 24 x 264 f32 staged once in LDS (25 KB), then r3's
// proven 4x4-microtile / 12-row sliding-window compute reads from LDS.
// Each global byte loaded ~1.5x (vs 9x cache-served redundancy in r3).
// Stores: 1KB contiguous per wave-row (proven clean: WRITE = 65 MB).

#define H 4096
#define W 4096
#define OH 4088
#define OW 4088
#define LROWS 24          // 16 output rows + 8 halo
#define LCW 264           // 256 output cols + 8 halo (word stride, %4==0)
#define NF4 (LCW / 4)     // 66 float4 per LDS row

__global__ __launch_bounds__(256, 4)
void conv9x9_kernel(const float* __restrict__ X,
                    const float* __restrict__ K,
                    const float* __restrict__ B,
                    float* __restrict__ out) {
    __shared__ float lds[LROWS * LCW];   // 25,344 B

    const int tid = threadIdx.x;
    const int bx = blockIdx.x;      // 16 col-tiles of 256
    const int by = blockIdx.y;      // 256 row-tiles of 16
    const int rin0 = by * 16;
    const int cin0 = bx * 256;

    // ---- stage 24 x 264 into LDS (each byte once; clamped edges only feed
    //      outputs masked at store) ----
    for (int idx = tid; idx < LROWS * NF4; idx += 256) {
        const int row = idx / NF4;
        const int c4  = idx - row * NF4;
        int gr = rin0 + row;     if (gr > H - 1) gr = H - 1;
        int gc = cin0 + c4 * 4;  if (gc > W - 4) gc = W - 4;   // stays 16B-aligned
        float4 v = *(const float4*)(X + (size_t)gr * W + gc);
        *(float4*)(&lds[row * LCW + c4 * 4]) = v;
    }
    __syncthreads();

    // ---- compute: r3's 4x4 micro-tile, 12-row sliding window, from LDS ----
    const int tx = tid & 63;        // 64 lanes across columns (4 cols each)
    const int ty = tid >> 6;        // 4 waves stacked vertically (4 rows each)
    const int lc = tx * 4;          // local col base (word)
    const int lr = ty * 4;          // local row base

    const float bias = B[0];
    float acc[4][4];
#pragma unroll
    for (int i = 0; i < 4; ++i)
#pragma unroll
        for (int j = 0; j < 4; ++j)
            acc[i][j] = bias;

#pragma unroll
    for (int t = 0; t < 12; ++t) {
        const float* rp = &lds[(lr + t) * LCW + lc];
        float seg[12];
#pragma unroll
        for (int q = 0; q < 3; ++q) {
            float4 v = *(const float4*)(rp + q * 4);
            seg[q * 4 + 0] = v.x; seg[q * 4 + 1] = v.y;
            seg[q * 4 + 2] = v.z; seg[q * 4 + 3] = v.w;
        }
        // input row t feeds output rows i = t-kr, kr in [0,8]
#pragma unroll
        for (int kr = 0; kr < 9; ++kr) {
            const int i = t - kr;
            if (i < 0 || i > 3) continue;    // compile-time pruned
#pragma unroll
            for (int kc = 0; kc < 9; ++kc) {
                const float kv = K[kr * 9 + kc];   // uniform -> SGPR
#pragma unroll
                for (int j = 0; j < 4; ++j)
                    acc[i][j] = fmaf(kv, seg[kc + j], acc[i][j]);
            }
        }
    }

    // ---- store: per wave-row 64 lanes x float4 = 1KB contiguous ----
    const int orow0 = by * 16 + lr;
    const int ocol  = cin0 + lc;
    if (ocol < OW) {
#pragma unroll
        for (int i = 0; i < 4; ++i) {
            const int orow = orow0 + i;
            if (orow < OH) {
                float4 v = { acc[i][0], acc[i][1], acc[i][2], acc[i][3] };
                *(float4*)(out + (size_t)orow * OW + ocol) = v;
            }
        }
    }
}

extern "C" void kernel_launch(void* const* d_in, const int* in_sizes, int n_in,
                              void* d_out, int out_size, void* d_ws, size_t ws_size,
                              hipStream_t stream) {
    const float* X = (const float*)d_in[0];
    const float* K = (const float*)d_in[1];
    const float* B = (const float*)d_in[2];
    float* out = (float*)d_out;

    dim3 grid(W / 256, (OH + 15) / 16);   // 16 x 256 = 4096 blocks
    dim3 block(256);
    conv9x9_kernel<<<grid, block, 0, stream>>>(X, K, B, out);
}